// Round 2
// baseline (1190.186 us; speedup 1.0000x reference)
//
#include <hip/hip_runtime.h>
#include <hip/hip_bf16.h>
#include <math.h>

#define N_D   4096
#define N_M   8192
#define NN    12288
#define EDG   196608
#define HID   512
#define NPAIR 65536

typedef __attribute__((ext_vector_type(8))) short short8;
typedef __attribute__((ext_vector_type(4))) float f32x4;

__device__ __forceinline__ unsigned short f32_to_bf16(float f) {
  unsigned int u = __float_as_uint(f);
  u += 0x7fffu + ((u >> 16) & 1u);
  return (unsigned short)(u >> 16);
}

// pack two fp32 -> two bf16 (round-nearest via +0x8000, v_perm pack)
__device__ __forceinline__ unsigned int pack_bf16x2(float a, float b) {
  unsigned int ua = __float_as_uint(a) + 0x8000u;
  unsigned int ub = __float_as_uint(b) + 0x8000u;
  return __builtin_amdgcn_perm(ub, ua, 0x07060302u);  // {hi16(ub), hi16(ua)}
}

// ---------------- transpose + cast: src [K][Nn] fp32 -> dst [Nn][K] bf16 ----
__global__ __launch_bounds__(256) void transpose_cast_k(
    const float* __restrict__ src, unsigned short* __restrict__ dst,
    int K, int Nn)
{
  __shared__ unsigned short t[64][65];
  const int bk = blockIdx.x * 64;
  const int bn = blockIdx.y * 64;
  const int tid = threadIdx.x;
  #pragma unroll
  for (int j = 0; j < 16; ++j) {
    int i = tid + 256 * j;
    int r = i >> 6, c = i & 63;
    t[r][c] = f32_to_bf16(src[(size_t)(bk + r) * Nn + bn + c]);
  }
  __syncthreads();
  #pragma unroll
  for (int j = 0; j < 16; ++j) {
    int i = tid + 256 * j;
    int r = i >> 6, c = i & 63;
    dst[(size_t)(bn + r) * K + bk + c] = t[c][r];
  }
}

// ---------------- graph preprocessing ----------------
__global__ __launch_bounds__(256) void deg_count_k(const int* __restrict__ dst,
                                                   int* __restrict__ deg)
{
  int e = blockIdx.x * 256 + threadIdx.x;
  atomicAdd(&deg[dst[e]], 1);
}

__global__ __launch_bounds__(256) void norm_k(const int* __restrict__ deg,
                                              float* __restrict__ nrm)
{
  int n = blockIdx.x * 256 + threadIdx.x;
  int d = deg[n];
  nrm[n] = 1.0f / sqrtf((float)(d < 1 ? 1 : d));
}

__global__ __launch_bounds__(1024) void scan_k(const int* __restrict__ deg,
                                               int* __restrict__ rp)
{
  __shared__ int sums[1024];
  const int t = threadIdx.x;
  int local[12];
  int s = 0;
  #pragma unroll
  for (int i = 0; i < 12; ++i) { local[i] = deg[t * 12 + i]; s += local[i]; }
  sums[t] = s;
  __syncthreads();
  for (int off = 1; off < 1024; off <<= 1) {
    int v = (t >= off) ? sums[t - off] : 0;
    __syncthreads();
    sums[t] += v;
    __syncthreads();
  }
  int run = (t == 0) ? 0 : sums[t - 1];
  #pragma unroll
  for (int i = 0; i < 12; ++i) { rp[t * 12 + i] = run; run += local[i]; }
  if (t == 1023) rp[12288] = run;
}

__global__ __launch_bounds__(256) void csr_fill_k(
    const int* __restrict__ src, const int* __restrict__ dst,
    const float* __restrict__ nrm, const int* __restrict__ rp,
    int* __restrict__ cur, int* __restrict__ col, float* __restrict__ wgt)
{
  int e = blockIdx.x * 256 + threadIdx.x;
  int d = dst[e];
  int p = rp[d] + atomicAdd(&cur[d], 1);
  int s = src[e];
  col[p] = s;
  wgt[p] = nrm[s] * nrm[d];
}

// ---------------- bf16 MFMA GEMM ----------------
// C[M,N](+ldc) = A[M,K] * Bt[N,K]^T ; A fp32 (AF32, converted in staging) or bf16.
// SPLITK>1: blockIdx.z = K-chunk; partial z written at C + z*M*ldc.
#define LDSP 72  // 64 + 8 bf16 pad -> worst 2-way bank aliasing (free, m136)

template<bool AF32, int SPLITK>
__global__ __launch_bounds__(256, 4) void gemm_k(
    const void* __restrict__ Av, const unsigned short* __restrict__ Bt,
    float* __restrict__ C, int M, int Ktot, int ldc)
{
  __shared__ unsigned short lA[128 * LDSP];
  __shared__ unsigned short lB[128 * LDSP];
  const int tid = threadIdx.x;
  const int lane = tid & 63;
  const int wave = tid >> 6;
  const int wm = (wave >> 1) * 64;
  const int wn = (wave & 1) * 64;
  const int m0 = blockIdx.y * 128;
  const int n0 = blockIdx.x * 128;
  const int kbeg = (SPLITK > 1) ? (int)blockIdx.z * (Ktot / SPLITK) : 0;
  float* Cz = (SPLITK > 1) ? C + (size_t)blockIdx.z * M * ldc : C;

  f32x4 acc[4][4];
  const f32x4 zero = {0.f, 0.f, 0.f, 0.f};
  #pragma unroll
  for (int i = 0; i < 4; ++i)
    #pragma unroll
    for (int j = 0; j < 4; ++j) acc[i][j] = zero;

  const int kTiles = (Ktot / SPLITK) / 64;
  for (int kt = 0; kt < kTiles; ++kt) {
    const int k0 = kbeg + kt * 64;
    __syncthreads();
    if (AF32) {
      const float* A = (const float*)Av;
      #pragma unroll
      for (int j = 0; j < 8; ++j) {
        int i = tid + 256 * j;          // 0..2047 over [row][col4]
        int r = i >> 4;
        int c4 = i & 15;
        const float4 v = *reinterpret_cast<const float4*>(
            &A[(size_t)(m0 + r) * Ktot + k0 + c4 * 4]);
        uint2 p;
        p.x = pack_bf16x2(v.x, v.y);
        p.y = pack_bf16x2(v.z, v.w);
        *reinterpret_cast<uint2*>(&lA[r * LDSP + c4 * 4]) = p;
      }
    } else {
      const unsigned short* A = (const unsigned short*)Av;
      #pragma unroll
      for (int j = 0; j < 4; ++j) {
        int i = tid + 256 * j;          // 0..1023 over [row][col8]
        int r = i >> 3;
        int c8 = (i & 7) * 8;
        const int4 v = *reinterpret_cast<const int4*>(
            &A[(size_t)(m0 + r) * Ktot + k0 + c8]);
        *reinterpret_cast<int4*>(&lA[r * LDSP + c8]) = v;
      }
    }
    #pragma unroll
    for (int j = 0; j < 4; ++j) {
      int i = tid + 256 * j;
      int r = i >> 3;
      int c8 = (i & 7) * 8;
      const int4 v = *reinterpret_cast<const int4*>(
          &Bt[(size_t)(n0 + r) * Ktot + k0 + c8]);
      *reinterpret_cast<int4*>(&lB[r * LDSP + c8]) = v;
    }
    __syncthreads();
    #pragma unroll
    for (int ks = 0; ks < 2; ++ks) {
      const int kk = ks * 32 + (lane >> 4) * 8;
      short8 af[4], bfr[4];
      #pragma unroll
      for (int mi = 0; mi < 4; ++mi)
        af[mi] = *reinterpret_cast<const short8*>(&lA[(wm + mi * 16 + (lane & 15)) * LDSP + kk]);
      #pragma unroll
      for (int ni = 0; ni < 4; ++ni)
        bfr[ni] = *reinterpret_cast<const short8*>(&lB[(wn + ni * 16 + (lane & 15)) * LDSP + kk]);
      #pragma unroll
      for (int mi = 0; mi < 4; ++mi)
        #pragma unroll
        for (int ni = 0; ni < 4; ++ni)
          acc[mi][ni] = __builtin_amdgcn_mfma_f32_16x16x32_bf16(af[mi], bfr[ni], acc[mi][ni], 0, 0, 0);
    }
  }
  // C/D layout col=lane&15, row=(lane>>4)*4+reg (m89-verified)
  #pragma unroll
  for (int mi = 0; mi < 4; ++mi) {
    #pragma unroll
    for (int ni = 0; ni < 4; ++ni) {
      const int colI = n0 + wn + ni * 16 + (lane & 15);
      const int rbase = m0 + wm + mi * 16 + (lane >> 4) * 4;
      #pragma unroll
      for (int r = 0; r < 4; ++r)
        Cz[(size_t)(rbase + r) * ldc + colI] = acc[mi][ni][r];
    }
  }
}

// ---------------- reduce SPLITK partials + cast to bf16 ----------------
template<int SPLITK>
__global__ __launch_bounds__(256) void reduce_cast_k(
    const float* __restrict__ P, unsigned short* __restrict__ out, int total)
{
  int i4 = (blockIdx.x * 256 + threadIdx.x) * 4;
  float4 s = *reinterpret_cast<const float4*>(&P[i4]);
  #pragma unroll
  for (int z = 1; z < SPLITK; ++z) {
    float4 v = *reinterpret_cast<const float4*>(&P[(size_t)z * total + i4]);
    s.x += v.x; s.y += v.y; s.z += v.z; s.w += v.w;
  }
  uint2 o2;
  o2.x = pack_bf16x2(s.x, s.y);
  o2.y = pack_bf16x2(s.z, s.w);
  *reinterpret_cast<uint2*>(&out[i4]) = o2;
}

// ---------------- SpMM: Tout[n,:] = Yk[n,:] + sum_e w_e * Tin[col_e,:] -----
__global__ __launch_bounds__(128) void spmm_k(
    const int* __restrict__ rp, const int* __restrict__ col,
    const float* __restrict__ wgt, const float* __restrict__ Tin, int ldin,
    const float* __restrict__ Yk, int ldy, const float* __restrict__ bias,
    float* __restrict__ Tout, int addBias)
{
  const int n = blockIdx.x;
  const int c0 = threadIdx.x * 4;
  float4 acc = *reinterpret_cast<const float4*>(&Yk[(size_t)n * ldy + c0]);
  const int e1 = rp[n + 1];
  int e = rp[n];
  for (; e + 1 < e1; e += 2) {
    int s0 = col[e], s1 = col[e + 1];
    float w0 = wgt[e], w1 = wgt[e + 1];
    float4 v0 = *reinterpret_cast<const float4*>(&Tin[(size_t)s0 * ldin + c0]);
    float4 v1 = *reinterpret_cast<const float4*>(&Tin[(size_t)s1 * ldin + c0]);
    acc.x += w0 * v0.x + w1 * v1.x;
    acc.y += w0 * v0.y + w1 * v1.y;
    acc.z += w0 * v0.z + w1 * v1.z;
    acc.w += w0 * v0.w + w1 * v1.w;
  }
  if (e < e1) {
    int s0 = col[e];
    float w0 = wgt[e];
    float4 v0 = *reinterpret_cast<const float4*>(&Tin[(size_t)s0 * ldin + c0]);
    acc.x += w0 * v0.x; acc.y += w0 * v0.y; acc.z += w0 * v0.z; acc.w += w0 * v0.w;
  }
  if (addBias) {
    float4 b4 = *reinterpret_cast<const float4*>(&bias[c0]);
    acc.x += b4.x; acc.y += b4.y; acc.z += b4.z; acc.w += b4.w;
  }
  *reinterpret_cast<float4*>(&Tout[(size_t)n * HID + c0]) = acc;
}

// ---------------- per-node predictor precompute ----------------
__global__ __launch_bounds__(128) void node_ab_g_k(
    const float* __restrict__ h, const float* __restrict__ Wp,
    float* __restrict__ a, float* __restrict__ b, float* __restrict__ g)
{
  const int n = blockIdx.x;
  const int tid = threadIdx.x;
  const int c0 = tid * 4;
  float4 hv = *reinterpret_cast<const float4*>(&h[(size_t)n * HID + c0]);
  float4 w1 = *reinterpret_cast<const float4*>(&Wp[c0]);
  float4 w2 = *reinterpret_cast<const float4*>(&Wp[HID + c0]);
  float4 w3 = *reinterpret_cast<const float4*>(&Wp[2 * HID + c0]);
  float pa = hv.x * w1.x + hv.y * w1.y + hv.z * w1.z + hv.w * w1.w;
  float pb = hv.x * w2.x + hv.y * w2.y + hv.z * w2.z + hv.w * w2.w;
  if (n < N_D) {
    float4 gv;
    gv.x = hv.x * w3.x; gv.y = hv.y * w3.y; gv.z = hv.z * w3.z; gv.w = hv.w * w3.w;
    *reinterpret_cast<float4*>(&g[(size_t)n * HID + c0]) = gv;
  }
  #pragma unroll
  for (int off = 32; off > 0; off >>= 1) {
    pa += __shfl_down(pa, off);
    pb += __shfl_down(pb, off);
  }
  __shared__ float sA[2], sB[2];
  const int lane = tid & 63, wv = tid >> 6;
  if (lane == 0) { sA[wv] = pa; sB[wv] = pb; }
  __syncthreads();
  if (tid == 0) { a[n] = sA[0] + sA[1]; b[n] = sB[0] + sB[1]; }
}

// ---------------- pair scoring: wave per pair ----------------
__global__ __launch_bounds__(256) void pairs_kernel(
    const int* __restrict__ dis, const int* __restrict__ mir,
    const float* __restrict__ h, const float* __restrict__ g,
    const float* __restrict__ a, const float* __restrict__ b,
    const float* __restrict__ bp, float* __restrict__ out)
{
  const int gw = (int)((blockIdx.x * 256 + threadIdx.x) >> 6);
  const int lane = threadIdx.x & 63;
  if (gw >= NPAIR) return;
  const int d = dis[gw];
  const int m = mir[gw];
  const float4* gr = reinterpret_cast<const float4*>(&g[(size_t)d * HID + lane * 8]);
  const float4* hr = reinterpret_cast<const float4*>(&h[(size_t)m * HID + lane * 8]);
  float4 g0 = gr[0], g1 = gr[1];
  float4 h0 = hr[0], h1 = hr[1];
  float s = g0.x * h0.x + g0.y * h0.y + g0.z * h0.z + g0.w * h0.w
          + g1.x * h1.x + g1.y * h1.y + g1.z * h1.z + g1.w * h1.w;
  #pragma unroll
  for (int off = 32; off > 0; off >>= 1) s += __shfl_down(s, off);
  if (lane == 0) {
    float logit = s + a[d] + b[m] + bp[0];
    out[gw] = 1.0f / (1.0f + expf(-logit));
  }
}

// ---------------- launcher ----------------
extern "C" void kernel_launch(void* const* d_in, const int* in_sizes, int n_in,
                              void* d_out, int out_size, void* d_ws, size_t ws_size,
                              hipStream_t stream)
{
  const float* d_sim = (const float*)d_in[0];
  const float* m_sim = (const float*)d_in[1];
  const int*   src   = (const int*)d_in[2];
  const int*   dst   = (const int*)d_in[3];
  const int*   dis   = (const int*)d_in[4];
  const int*   mir   = (const int*)d_in[5];
  const float* Wd    = (const float*)d_in[6];
  const float* Wm    = (const float*)d_in[7];
  const float* Wf    = (const float*)d_in[8];
  const float* bf    = (const float*)d_in[9];
  const float* Wp    = (const float*)d_in[10];
  const float* bp    = (const float*)d_in[11];
  float* out = (float*)d_out;

  const size_t SZ_T  = (size_t)NN * HID * 4;        // 25165824
  const size_t SZ_XB = (size_t)NN * HID * 2;        // 12582912
  const size_t PART4 = 4 * SZ_T;                    // 100663296
  const size_t PART2 = 2 * SZ_T;                    //  50331648
  const size_t YALL  = (size_t)NN * 2560 * 4;       // 125829120

  // plan: 0 = splitK4 + fused Y_all; 1 = splitK4 + per-k Y; 2 = splitK2 + per-k Y
  int plan; size_t R1sz;
  if      (ws_size >= YALL  + 80000000 + 4096) { plan = 0; R1sz = YALL;  }
  else if (ws_size >= PART4 + 80000000 + 4096) { plan = 1; R1sz = PART4; }
  else                                         { plan = 2; R1sz = PART2; }

  char* p = (char*)d_ws;
  char* R1 = p;                 p += R1sz;
  unsigned short* Xb  = (unsigned short*)p;  p += SZ_XB;
  float* T0 = (float*)p;        p += SZ_T;
  float* T1 = (float*)p;        p += SZ_T;
  unsigned short* WdT = (unsigned short*)p;  p += (size_t)512 * 4096 * 2;
  unsigned short* WmT = (unsigned short*)p;  p += (size_t)512 * 8192 * 2;
  unsigned short* WfT = (unsigned short*)p;  p += (size_t)2560 * 512 * 2;
  int*   deg = (int*)p;         p += 49152;
  float* nrm = (float*)p;       p += 49152;
  int*   rp  = (int*)p;         p += 49664;
  int*   cur = (int*)p;         p += 49152;
  int*   col = (int*)p;         p += (size_t)EDG * 4;
  float* wgt = (float*)p;       p += (size_t)EDG * 4;
  float* av  = (float*)p;       p += 49152;
  float* bv  = (float*)p;       p += 49152;
  float* G   = (float*)R1;      // alias: used only after Y buffers are dead

  // ---- pack weights to bf16, transposed [N][K] ----
  transpose_cast_k<<<dim3(64, 8), 256, 0, stream>>>(Wd, WdT, 4096, 512);
  transpose_cast_k<<<dim3(128, 8), 256, 0, stream>>>(Wm, WmT, 8192, 512);
  for (int k = 0; k < 5; ++k)
    transpose_cast_k<<<dim3(8, 8), 256, 0, stream>>>(
        Wf + (size_t)k * 512 * 512, WfT + (size_t)k * 512 * 512, 512, 512);

  // ---- graph: degrees, norms, CSR by dst ----
  hipMemsetAsync(deg, 0, 49152, stream);
  hipMemsetAsync(cur, 0, 49152, stream);
  deg_count_k<<<EDG / 256, 256, 0, stream>>>(dst, deg);
  norm_k<<<NN / 256, 256, 0, stream>>>(deg, nrm);
  scan_k<<<1, 1024, 0, stream>>>(deg, rp);
  csr_fill_k<<<EDG / 256, 256, 0, stream>>>(src, dst, nrm, rp, cur, col, wgt);

  // ---- X = [d_sim@Wd ; m_sim@Wm] (split-K partials -> reduce+cast to bf16) --
  float* Pd = (float*)R1;
  if (plan <= 1) {
    float* Pm = Pd + (size_t)4 * 4096 * 512;
    gemm_k<true, 4><<<dim3(4, 32, 4), 256, 0, stream>>>(d_sim, WdT, Pd, 4096, 4096, 512);
    gemm_k<true, 4><<<dim3(4, 64, 4), 256, 0, stream>>>(m_sim, WmT, Pm, 8192, 8192, 512);
    reduce_cast_k<4><<<2048, 256, 0, stream>>>(Pd, Xb, 4096 * 512);
    reduce_cast_k<4><<<4096, 256, 0, stream>>>(Pm, Xb + (size_t)4096 * 512, 8192 * 512);
  } else {
    float* Pm = Pd + (size_t)2 * 4096 * 512;
    gemm_k<true, 2><<<dim3(4, 32, 2), 256, 0, stream>>>(d_sim, WdT, Pd, 4096, 4096, 512);
    gemm_k<true, 2><<<dim3(4, 64, 2), 256, 0, stream>>>(m_sim, WmT, Pm, 8192, 8192, 512);
    reduce_cast_k<2><<<2048, 256, 0, stream>>>(Pd, Xb, 4096 * 512);
    reduce_cast_k<2><<<4096, 256, 0, stream>>>(Pm, Xb + (size_t)4096 * 512, 8192 * 512);
  }

  // ---- Horner: h = Y0 + A(Y1 + A(Y2 + A(Y3 + A*Y4))) + bf ----
  if (plan == 0) {
    float* Yall = (float*)R1;
    gemm_k<false, 1><<<dim3(20, 96, 1), 256, 0, stream>>>(Xb, WfT, Yall, NN, 512, 2560);
    spmm_k<<<NN, 128, 0, stream>>>(rp, col, wgt, Yall + 4 * 512, 2560, Yall + 3 * 512, 2560, bf, T1, 0);
    spmm_k<<<NN, 128, 0, stream>>>(rp, col, wgt, T1, 512, Yall + 2 * 512, 2560, bf, T0, 0);
    spmm_k<<<NN, 128, 0, stream>>>(rp, col, wgt, T0, 512, Yall + 1 * 512, 2560, bf, T1, 0);
    spmm_k<<<NN, 128, 0, stream>>>(rp, col, wgt, T1, 512, Yall + 0 * 512, 2560, bf, T0, 1);
  } else {
    float* Q0 = (float*)R1;
    float* Q1 = Q0 + (size_t)NN * 512;
    gemm_k<false, 1><<<dim3(4, 96, 1), 256, 0, stream>>>(Xb, WfT + (size_t)4 * 512 * 512, Q0, NN, 512, 512);
    gemm_k<false, 1><<<dim3(4, 96, 1), 256, 0, stream>>>(Xb, WfT + (size_t)3 * 512 * 512, Q1, NN, 512, 512);
    spmm_k<<<NN, 128, 0, stream>>>(rp, col, wgt, Q0, 512, Q1, 512, bf, T1, 0);
    gemm_k<false, 1><<<dim3(4, 96, 1), 256, 0, stream>>>(Xb, WfT + (size_t)2 * 512 * 512, Q1, NN, 512, 512);
    spmm_k<<<NN, 128, 0, stream>>>(rp, col, wgt, T1, 512, Q1, 512, bf, T0, 0);
    gemm_k<false, 1><<<dim3(4, 96, 1), 256, 0, stream>>>(Xb, WfT + (size_t)1 * 512 * 512, Q1, NN, 512, 512);
    spmm_k<<<NN, 128, 0, stream>>>(rp, col, wgt, T0, 512, Q1, 512, bf, T1, 0);
    gemm_k<false, 1><<<dim3(4, 96, 1), 256, 0, stream>>>(Xb, WfT + (size_t)0 * 512 * 512, Q1, NN, 512, 512);
    spmm_k<<<NN, 128, 0, stream>>>(rp, col, wgt, T1, 512, Q1, 512, bf, T0, 1);
  }
  float* h = T0;

  // ---- predictor ----
  node_ab_g_k<<<NN, 128, 0, stream>>>(h, Wp, av, bv, G);
  pairs_kernel<<<NPAIR / 4, 256, 0, stream>>>(dis, mir, h, G, av, bv, bp, out);
}

// Round 3
// 901.229 us; speedup vs baseline: 1.3206x; 1.3206x over previous
//
#include <hip/hip_runtime.h>
#include <hip/hip_bf16.h>
#include <math.h>

#define N_D   4096
#define N_M   8192
#define NN    12288
#define EDG   196608
#define HID   512
#define NPAIR 65536

typedef __attribute__((ext_vector_type(8))) short short8;
typedef __attribute__((ext_vector_type(4))) float f32x4;

__device__ __forceinline__ unsigned short f32_to_bf16(float f) {
  unsigned int u = __float_as_uint(f);
  u += 0x7fffu + ((u >> 16) & 1u);
  return (unsigned short)(u >> 16);
}

__device__ __forceinline__ unsigned int pack_bf16x2(float a, float b) {
  unsigned int ua = __float_as_uint(a) + 0x8000u;
  unsigned int ub = __float_as_uint(b) + 0x8000u;
  return __builtin_amdgcn_perm(ub, ua, 0x07060302u);
}

// async 16B global -> LDS (wave-uniform LDS base + lane*16)
__device__ __forceinline__ void glds16(const void* g, void* l) {
  __builtin_amdgcn_global_load_lds(
      (const __attribute__((address_space(1))) unsigned int*)g,
      (__attribute__((address_space(3))) unsigned int*)l, 16, 0, 0);
}

// ---------------- transpose + cast: src [K][Nn] fp32 -> dst [Nn][K] bf16 ----
__global__ __launch_bounds__(256) void transpose_cast_k(
    const float* __restrict__ src, unsigned short* __restrict__ dst,
    int K, int Nn)
{
  __shared__ unsigned short t[64][65];
  const int bk = blockIdx.x * 64;
  const int bn = blockIdx.y * 64;
  const int tid = threadIdx.x;
  #pragma unroll
  for (int j = 0; j < 16; ++j) {
    int i = tid + 256 * j;
    int r = i >> 6, c = i & 63;
    t[r][c] = f32_to_bf16(src[(size_t)(bk + r) * Nn + bn + c]);
  }
  __syncthreads();
  #pragma unroll
  for (int j = 0; j < 16; ++j) {
    int i = tid + 256 * j;
    int r = i >> 6, c = i & 63;
    dst[(size_t)(bn + r) * K + bk + c] = t[c][r];
  }
}

// ---------------- graph preprocessing ----------------
__global__ __launch_bounds__(256) void deg_count_k(const int* __restrict__ dst,
                                                   int* __restrict__ deg)
{
  int e = blockIdx.x * 256 + threadIdx.x;
  atomicAdd(&deg[dst[e]], 1);
}

__global__ __launch_bounds__(256) void norm_k(const int* __restrict__ deg,
                                              float* __restrict__ nrm)
{
  int n = blockIdx.x * 256 + threadIdx.x;
  int d = deg[n];
  nrm[n] = 1.0f / sqrtf((float)(d < 1 ? 1 : d));
}

__global__ __launch_bounds__(1024) void scan_k(const int* __restrict__ deg,
                                               int* __restrict__ rp)
{
  __shared__ int sums[1024];
  const int t = threadIdx.x;
  int local[12];
  int s = 0;
  #pragma unroll
  for (int i = 0; i < 12; ++i) { local[i] = deg[t * 12 + i]; s += local[i]; }
  sums[t] = s;
  __syncthreads();
  for (int off = 1; off < 1024; off <<= 1) {
    int v = (t >= off) ? sums[t - off] : 0;
    __syncthreads();
    sums[t] += v;
    __syncthreads();
  }
  int run = (t == 0) ? 0 : sums[t - 1];
  #pragma unroll
  for (int i = 0; i < 12; ++i) { rp[t * 12 + i] = run; run += local[i]; }
  if (t == 1023) rp[12288] = run;
}

__global__ __launch_bounds__(256) void csr_fill_k(
    const int* __restrict__ src, const int* __restrict__ dst,
    const float* __restrict__ nrm, const int* __restrict__ rp,
    int* __restrict__ cur, int* __restrict__ col, float* __restrict__ wgt)
{
  int e = blockIdx.x * 256 + threadIdx.x;
  int d = dst[e];
  int p = rp[d] + atomicAdd(&cur[d], 1);
  int s = src[e];
  col[p] = s;
  wgt[p] = nrm[s] * nrm[d];
}

// ---------------- big-tile MFMA GEMM ----------------
// C[M, >=512] = A[M,K] * Bt[512-slice, K]^T.  Block: BM=128 x BN=512, 512 thr.
// A fetched EXACTLY once per z-chunk (full N in one block).
// B: global_load_lds (async, 16B) -> double-buffered swizzled LDS.
// A: VGPR prefetch (+ fp32->bf16 convert when AF32) -> single swizzled LDS buf.
// Swizzle: element (r,k) at byte r*128 + ((k>>3 ^ (r&7))*16 + (k&7)*2.
// grid: x = 512-col slice of Bt/C, y = m-block, z = split-K chunk.
template<bool AF32>
__global__ __launch_bounds__(512, 2) void gemm_big(
    const void* __restrict__ Av, const unsigned short* __restrict__ Bt,
    float* __restrict__ C, int M, int Ktot, int kchunk, int ldc)
{
  __shared__ unsigned short lA[128 * 64];        // 16 KB
  __shared__ unsigned short lB[2][512 * 64];     // 2 x 64 KB  (total 144 KB)
  const int t = threadIdx.x;
  const int w = t >> 6;
  const int l = t & 63;
  const int wm = (w >> 2) * 64;
  const int wn = (w & 3) * 128;
  const int m0 = blockIdx.y * 128;
  const int n0 = blockIdx.x * 512;
  const int kbeg = blockIdx.z * kchunk;
  float* Cz = C + (size_t)blockIdx.z * M * ldc;

  f32x4 acc[4][8];
  const f32x4 zero = {0.f, 0.f, 0.f, 0.f};
  #pragma unroll
  for (int i = 0; i < 4; ++i)
    #pragma unroll
    for (int j = 0; j < 8; ++j) acc[i][j] = zero;

  float4 aP32[4];
  int4   aP16[2];

  // ---- staging helpers (inlined via macros of loops) ----
  const int iters = kchunk / 64;

  // prologue: stage B(0) async, load A(0) regs
  #pragma unroll
  for (int j = 0; j < 8; ++j) {
    int i = t + 512 * j;
    int row = i >> 3;
    int gcol = ((i & 7) ^ (row & 7)) << 3;
    glds16(Bt + (size_t)(n0 + row) * Ktot + kbeg + gcol,
           &lB[0][(size_t)(j * 512 + w * 64) * 8]);
  }
  if (AF32) {
    const float* A = (const float*)Av;
    #pragma unroll
    for (int j = 0; j < 4; ++j) {
      int i = t + 512 * j;
      int row = i >> 4, c4s = i & 15;
      int gcol = ((((c4s >> 1) ^ (row & 7)) << 3)) + ((c4s & 1) << 2);
      aP32[j] = *reinterpret_cast<const float4*>(&A[(size_t)(m0 + row) * Ktot + kbeg + gcol]);
    }
  } else {
    const unsigned short* A = (const unsigned short*)Av;
    #pragma unroll
    for (int j = 0; j < 2; ++j) {
      int i = t + 512 * j;
      int row = i >> 3;
      int gcol = ((i & 7) ^ (row & 7)) << 3;
      aP16[j] = *reinterpret_cast<const int4*>(&A[(size_t)(m0 + row) * Ktot + kbeg + gcol]);
    }
  }
  // write A(0) to LDS
  if (AF32) {
    #pragma unroll
    for (int j = 0; j < 4; ++j) {
      int i = t + 512 * j;
      int row = i >> 4, c4s = i & 15;
      uint2 p;
      p.x = pack_bf16x2(aP32[j].x, aP32[j].y);
      p.y = pack_bf16x2(aP32[j].z, aP32[j].w);
      *reinterpret_cast<uint2*>(&lA[row * 64 + c4s * 4]) = p;
    }
  } else {
    #pragma unroll
    for (int j = 0; j < 2; ++j) {
      int i = t + 512 * j;
      int row = i >> 3;
      *reinterpret_cast<int4*>(&lA[row * 64 + (i & 7) * 8]) = aP16[j];
    }
  }
  __syncthreads();   // drains glds buf0 (compiler vmcnt(0) before barrier)

  int bi = 0;
  for (int kt = 0; kt < iters; ++kt) {
    const int kn = kbeg + (kt + 1) * 64;
    if (kt + 1 < iters) {
      // async-stage B(k+1) into other buffer; prefetch A(k+1) into regs
      #pragma unroll
      for (int j = 0; j < 8; ++j) {
        int i = t + 512 * j;
        int row = i >> 3;
        int gcol = ((i & 7) ^ (row & 7)) << 3;
        glds16(Bt + (size_t)(n0 + row) * Ktot + kn + gcol,
               &lB[bi ^ 1][(size_t)(j * 512 + w * 64) * 8]);
      }
      if (AF32) {
        const float* A = (const float*)Av;
        #pragma unroll
        for (int j = 0; j < 4; ++j) {
          int i = t + 512 * j;
          int row = i >> 4, c4s = i & 15;
          int gcol = ((((c4s >> 1) ^ (row & 7)) << 3)) + ((c4s & 1) << 2);
          aP32[j] = *reinterpret_cast<const float4*>(&A[(size_t)(m0 + row) * Ktot + kn + gcol]);
        }
      } else {
        const unsigned short* A = (const unsigned short*)Av;
        #pragma unroll
        for (int j = 0; j < 2; ++j) {
          int i = t + 512 * j;
          int row = i >> 3;
          int gcol = ((i & 7) ^ (row & 7)) << 3;
          aP16[j] = *reinterpret_cast<const int4*>(&A[(size_t)(m0 + row) * Ktot + kn + gcol]);
        }
      }
    }
    // ---- MFMA phase (reads lA, lB[bi]) ----
    const unsigned short* lBc = &lB[bi][0];
    #pragma unroll
    for (int ks = 0; ks < 2; ++ks) {
      const int kc = ks * 4 + (l >> 4);           // k-chunk 0..7
      const int co = ((kc ^ (l & 7)) << 3);       // swizzled chunk offset (shorts)
      short8 af[4];
      #pragma unroll
      for (int mi = 0; mi < 4; ++mi) {
        int row = wm + mi * 16 + (l & 15);
        af[mi] = *reinterpret_cast<const short8*>(&lA[row * 64 + co]);
      }
      #pragma unroll
      for (int ni = 0; ni < 8; ++ni) {
        int brow = wn + ni * 16 + (l & 15);
        short8 bfr = *reinterpret_cast<const short8*>(&lBc[brow * 64 + co]);
        #pragma unroll
        for (int mi = 0; mi < 4; ++mi)
          acc[mi][ni] = __builtin_amdgcn_mfma_f32_16x16x32_bf16(af[mi], bfr, acc[mi][ni], 0, 0, 0);
      }
    }
    __syncthreads();           // all waves done reading lA / lB[bi]
    if (kt + 1 < iters) {
      if (AF32) {
        #pragma unroll
        for (int j = 0; j < 4; ++j) {
          int i = t + 512 * j;
          int row = i >> 4, c4s = i & 15;
          uint2 p;
          p.x = pack_bf16x2(aP32[j].x, aP32[j].y);
          p.y = pack_bf16x2(aP32[j].z, aP32[j].w);
          *reinterpret_cast<uint2*>(&lA[row * 64 + c4s * 4]) = p;
        }
      } else {
        #pragma unroll
        for (int j = 0; j < 2; ++j) {
          int i = t + 512 * j;
          int row = i >> 3;
          *reinterpret_cast<int4*>(&lA[row * 64 + (i & 7) * 8]) = aP16[j];
        }
      }
    }
    __syncthreads();           // A(k+1) visible; glds(k+1) drained by barrier
    bi ^= 1;
  }
  // epilogue: C/D layout col=lane&15, row=(lane>>4)*4+reg (m89-verified)
  #pragma unroll
  for (int mi = 0; mi < 4; ++mi) {
    #pragma unroll
    for (int ni = 0; ni < 8; ++ni) {
      const int colI = n0 + wn + ni * 16 + (l & 15);
      const int rbase = m0 + wm + mi * 16 + (l >> 4) * 4;
      #pragma unroll
      for (int r = 0; r < 4; ++r)
        Cz[(size_t)(rbase + r) * ldc + colI] = acc[mi][ni][r];
    }
  }
}

// ---------------- reduce SPLITK partials + cast to bf16 ----------------
template<int SPLITK>
__global__ __launch_bounds__(256) void reduce_cast_k(
    const float* __restrict__ P, unsigned short* __restrict__ out, int total)
{
  int i4 = (blockIdx.x * 256 + threadIdx.x) * 4;
  float4 s = *reinterpret_cast<const float4*>(&P[i4]);
  #pragma unroll
  for (int z = 1; z < SPLITK; ++z) {
    float4 v = *reinterpret_cast<const float4*>(&P[(size_t)z * total + i4]);
    s.x += v.x; s.y += v.y; s.z += v.z; s.w += v.w;
  }
  uint2 o2;
  o2.x = pack_bf16x2(s.x, s.y);
  o2.y = pack_bf16x2(s.z, s.w);
  *reinterpret_cast<uint2*>(&out[i4]) = o2;
}

// ---------------- SpMM: Tout[n,:] = Yk[n,:] + sum_e w_e * Tin[col_e,:] -----
__global__ __launch_bounds__(128) void spmm_k(
    const int* __restrict__ rp, const int* __restrict__ col,
    const float* __restrict__ wgt, const float* __restrict__ Tin, int ldin,
    const float* __restrict__ Yk, int ldy, const float* __restrict__ bias,
    float* __restrict__ Tout, int addBias)
{
  const int n = blockIdx.x;
  const int c0 = threadIdx.x * 4;
  float4 acc = *reinterpret_cast<const float4*>(&Yk[(size_t)n * ldy + c0]);
  const int e1 = rp[n + 1];
  int e = rp[n];
  for (; e + 1 < e1; e += 2) {
    int s0 = col[e], s1 = col[e + 1];
    float w0 = wgt[e], w1 = wgt[e + 1];
    float4 v0 = *reinterpret_cast<const float4*>(&Tin[(size_t)s0 * ldin + c0]);
    float4 v1 = *reinterpret_cast<const float4*>(&Tin[(size_t)s1 * ldin + c0]);
    acc.x += w0 * v0.x + w1 * v1.x;
    acc.y += w0 * v0.y + w1 * v1.y;
    acc.z += w0 * v0.z + w1 * v1.z;
    acc.w += w0 * v0.w + w1 * v1.w;
  }
  if (e < e1) {
    int s0 = col[e];
    float w0 = wgt[e];
    float4 v0 = *reinterpret_cast<const float4*>(&Tin[(size_t)s0 * ldin + c0]);
    acc.x += w0 * v0.x; acc.y += w0 * v0.y; acc.z += w0 * v0.z; acc.w += w0 * v0.w;
  }
  if (addBias) {
    float4 b4 = *reinterpret_cast<const float4*>(&bias[c0]);
    acc.x += b4.x; acc.y += b4.y; acc.z += b4.z; acc.w += b4.w;
  }
  *reinterpret_cast<float4*>(&Tout[(size_t)n * HID + c0]) = acc;
}

// ---------------- per-node predictor precompute ----------------
__global__ __launch_bounds__(128) void node_ab_g_k(
    const float* __restrict__ h, const float* __restrict__ Wp,
    float* __restrict__ a, float* __restrict__ b, float* __restrict__ g)
{
  const int n = blockIdx.x;
  const int tid = threadIdx.x;
  const int c0 = tid * 4;
  float4 hv = *reinterpret_cast<const float4*>(&h[(size_t)n * HID + c0]);
  float4 w1 = *reinterpret_cast<const float4*>(&Wp[c0]);
  float4 w2 = *reinterpret_cast<const float4*>(&Wp[HID + c0]);
  float4 w3 = *reinterpret_cast<const float4*>(&Wp[2 * HID + c0]);
  float pa = hv.x * w1.x + hv.y * w1.y + hv.z * w1.z + hv.w * w1.w;
  float pb = hv.x * w2.x + hv.y * w2.y + hv.z * w2.z + hv.w * w2.w;
  if (n < N_D) {
    float4 gv;
    gv.x = hv.x * w3.x; gv.y = hv.y * w3.y; gv.z = hv.z * w3.z; gv.w = hv.w * w3.w;
    *reinterpret_cast<float4*>(&g[(size_t)n * HID + c0]) = gv;
  }
  #pragma unroll
  for (int off = 32; off > 0; off >>= 1) {
    pa += __shfl_down(pa, off);
    pb += __shfl_down(pb, off);
  }
  __shared__ float sA[2], sB[2];
  const int lane = tid & 63, wv = tid >> 6;
  if (lane == 0) { sA[wv] = pa; sB[wv] = pb; }
  __syncthreads();
  if (tid == 0) { a[n] = sA[0] + sA[1]; b[n] = sB[0] + sB[1]; }
}

// ---------------- pair scoring: wave per pair ----------------
__global__ __launch_bounds__(256) void pairs_kernel(
    const int* __restrict__ dis, const int* __restrict__ mir,
    const float* __restrict__ h, const float* __restrict__ g,
    const float* __restrict__ a, const float* __restrict__ b,
    const float* __restrict__ bp, float* __restrict__ out)
{
  const int gw = (int)((blockIdx.x * 256 + threadIdx.x) >> 6);
  const int lane = threadIdx.x & 63;
  if (gw >= NPAIR) return;
  const int d = dis[gw];
  const int m = mir[gw];
  const float4* gr = reinterpret_cast<const float4*>(&g[(size_t)d * HID + lane * 8]);
  const float4* hr = reinterpret_cast<const float4*>(&h[(size_t)m * HID + lane * 8]);
  float4 g0 = gr[0], g1 = gr[1];
  float4 h0 = hr[0], h1 = hr[1];
  float s = g0.x * h0.x + g0.y * h0.y + g0.z * h0.z + g0.w * h0.w
          + g1.x * h1.x + g1.y * h1.y + g1.z * h1.z + g1.w * h1.w;
  #pragma unroll
  for (int off = 32; off > 0; off >>= 1) s += __shfl_down(s, off);
  if (lane == 0) {
    float logit = s + a[d] + b[m] + bp[0];
    out[gw] = 1.0f / (1.0f + expf(-logit));
  }
}

// ---------------- launcher ----------------
extern "C" void kernel_launch(void* const* d_in, const int* in_sizes, int n_in,
                              void* d_out, int out_size, void* d_ws, size_t ws_size,
                              hipStream_t stream)
{
  const float* d_sim = (const float*)d_in[0];
  const float* m_sim = (const float*)d_in[1];
  const int*   src   = (const int*)d_in[2];
  const int*   dst   = (const int*)d_in[3];
  const int*   dis   = (const int*)d_in[4];
  const int*   mir   = (const int*)d_in[5];
  const float* Wd    = (const float*)d_in[6];
  const float* Wm    = (const float*)d_in[7];
  const float* Wf    = (const float*)d_in[8];
  const float* bf    = (const float*)d_in[9];
  const float* Wp    = (const float*)d_in[10];
  const float* bp    = (const float*)d_in[11];
  float* out = (float*)d_out;

  const size_t SZ_T  = (size_t)NN * HID * 4;            // 25165824
  const size_t SZ_XB = (size_t)NN * HID * 2;            // 12582912
  const size_t SZ_PD8 = (size_t)8 * 4096 * 512 * 4;     // 67108864
  const size_t SZ_PM4 = (size_t)4 * 8192 * 512 * 4;     // 67108864
  const size_t SZ_PD2 = (size_t)2 * 4096 * 512 * 4;     // 16777216
  const size_t SZ_PM2 = (size_t)2 * 8192 * 512 * 4;     // 33554432
  const size_t REST = SZ_XB + 2 * SZ_T + (size_t)512*4096*2 + (size_t)512*8192*2
                    + (size_t)2560*512*2 + 49152*4 + 49664 + (size_t)EDG*8 + 2*49152 + 65536;

  const int planA = (ws_size >= SZ_PD8 + SZ_PM4 + REST);
  const size_t R1sz = planA ? (SZ_PD8 + SZ_PM4) : (SZ_PD2 + SZ_PM2);

  char* p = (char*)d_ws;
  char* R1 = p;                 p += R1sz;
  unsigned short* Xb  = (unsigned short*)p;  p += SZ_XB;
  float* T0 = (float*)p;        p += SZ_T;
  float* T1 = (float*)p;        p += SZ_T;
  unsigned short* WdT = (unsigned short*)p;  p += (size_t)512 * 4096 * 2;
  unsigned short* WmT = (unsigned short*)p;  p += (size_t)512 * 8192 * 2;
  unsigned short* WfT = (unsigned short*)p;  p += (size_t)2560 * 512 * 2;
  int*   deg = (int*)p;         p += 49152;
  float* nrm = (float*)p;       p += 49152;
  int*   rp  = (int*)p;         p += 49664;
  int*   cur = (int*)p;         p += 49152;
  int*   col = (int*)p;         p += (size_t)EDG * 4;
  float* wgt = (float*)p;       p += (size_t)EDG * 4;
  float* av  = (float*)p;       p += 49152;
  float* bv  = (float*)p;       p += 49152;
  float* G   = T1;              // alias: T1 dead after last spmm (h=T0)

  // ---- pack weights to bf16, transposed [N][K] ----
  transpose_cast_k<<<dim3(64, 8), 256, 0, stream>>>(Wd, WdT, 4096, 512);
  transpose_cast_k<<<dim3(128, 8), 256, 0, stream>>>(Wm, WmT, 8192, 512);
  for (int k = 0; k < 5; ++k)
    transpose_cast_k<<<dim3(8, 8), 256, 0, stream>>>(
        Wf + (size_t)k * 512 * 512, WfT + (size_t)k * 512 * 512, 512, 512);

  // ---- graph: degrees, norms, CSR by dst ----
  hipMemsetAsync(deg, 0, 49152, stream);
  hipMemsetAsync(cur, 0, 49152, stream);
  deg_count_k<<<EDG / 256, 256, 0, stream>>>(dst, deg);
  norm_k<<<NN / 256, 256, 0, stream>>>(deg, nrm);
  scan_k<<<1, 1024, 0, stream>>>(deg, rp);
  csr_fill_k<<<EDG / 256, 256, 0, stream>>>(src, dst, nrm, rp, cur, col, wgt);

  // ---- X = [d_sim@Wd ; m_sim@Wm] : A fetched once, split-K to fill 256 CUs --
  if (planA) {
    float* Pd = (float*)R1;
    float* Pm = (float*)(R1 + SZ_PD8);
    gemm_big<true><<<dim3(1, 32, 8), 512, 0, stream>>>(d_sim, WdT, Pd, 4096, 4096, 512, 512);
    gemm_big<true><<<dim3(1, 64, 4), 512, 0, stream>>>(m_sim, WmT, Pm, 8192, 8192, 2048, 512);
    reduce_cast_k<8><<<2048, 256, 0, stream>>>(Pd, Xb, 4096 * 512);
    reduce_cast_k<4><<<4096, 256, 0, stream>>>(Pm, Xb + (size_t)4096 * 512, 8192 * 512);
  } else {
    float* Pd = (float*)R1;
    float* Pm = (float*)(R1 + SZ_PD2);
    gemm_big<true><<<dim3(1, 32, 2), 512, 0, stream>>>(d_sim, WdT, Pd, 4096, 4096, 2048, 512);
    gemm_big<true><<<dim3(1, 64, 2), 512, 0, stream>>>(m_sim, WmT, Pm, 8192, 8192, 4096, 512);
    reduce_cast_k<2><<<2048, 256, 0, stream>>>(Pd, Xb, 4096 * 512);
    reduce_cast_k<2><<<4096, 256, 0, stream>>>(Pm, Xb + (size_t)4096 * 512, 8192 * 512);
  }

  // ---- Horner: h = Y0 + A(Y1 + A(Y2 + A(Y3 + A*Y4))) + bf ----
  if (planA) {
    float* Yall = (float*)R1;   // 12288 x 2560 fp32, aliases partials
    gemm_big<false><<<dim3(5, 96, 1), 512, 0, stream>>>(Xb, WfT, Yall, NN, 512, 512, 2560);
    spmm_k<<<NN, 128, 0, stream>>>(rp, col, wgt, Yall + 4 * 512, 2560, Yall + 3 * 512, 2560, bf, T1, 0);
    spmm_k<<<NN, 128, 0, stream>>>(rp, col, wgt, T1, 512, Yall + 2 * 512, 2560, bf, T0, 0);
    spmm_k<<<NN, 128, 0, stream>>>(rp, col, wgt, T0, 512, Yall + 1 * 512, 2560, bf, T1, 0);
    spmm_k<<<NN, 128, 0, stream>>>(rp, col, wgt, T1, 512, Yall + 0 * 512, 2560, bf, T0, 1);
  } else {
    float* Q = (float*)R1;      // one 25 MB Y-slice at a time
    gemm_big<false><<<dim3(1, 96, 1), 512, 0, stream>>>(Xb, WfT + (size_t)4 * 512 * 512, T1, NN, 512, 512, 512);
    gemm_big<false><<<dim3(1, 96, 1), 512, 0, stream>>>(Xb, WfT + (size_t)3 * 512 * 512, Q, NN, 512, 512, 512);
    spmm_k<<<NN, 128, 0, stream>>>(rp, col, wgt, T1, 512, Q, 512, bf, T0, 0);
    gemm_big<false><<<dim3(1, 96, 1), 512, 0, stream>>>(Xb, WfT + (size_t)2 * 512 * 512, Q, NN, 512, 512, 512);
    spmm_k<<<NN, 128, 0, stream>>>(rp, col, wgt, T0, 512, Q, 512, bf, T1, 0);
    gemm_big<false><<<dim3(1, 96, 1), 512, 0, stream>>>(Xb, WfT + (size_t)1 * 512 * 512, Q, NN, 512, 512, 512);
    spmm_k<<<NN, 128, 0, stream>>>(rp, col, wgt, T1, 512, Q, 512, bf, T0, 0);
    gemm_big<false><<<dim3(1, 96, 1), 512, 0, stream>>>(Xb, WfT + (size_t)0 * 512 * 512, Q, NN, 512, 512, 512);
    spmm_k<<<NN, 128, 0, stream>>>(rp, col, wgt, T0, 512, Q, 512, bf, T1, 1);
  }
  float* h = planA ? T0 : T1;

  // ---- predictor ----
  node_ab_g_k<<<NN, 128, 0, stream>>>(h, Wp, av, bv, G);
  pairs_kernel<<<NPAIR / 4, 256, 0, stream>>>(dis, mir, h, G, av, bv, bp, out);
}

// Round 4
// 773.485 us; speedup vs baseline: 1.5387x; 1.1652x over previous
//
#include <hip/hip_runtime.h>
#include <hip/hip_bf16.h>
#include <math.h>

#define N_D   4096
#define N_M   8192
#define NN    12288
#define EDG   196608
#define HID   512
#define NPAIR 65536

typedef __attribute__((ext_vector_type(8))) short short8;
typedef __attribute__((ext_vector_type(4))) float f32x4;

__device__ __forceinline__ unsigned short f32_to_bf16(float f) {
  unsigned int u = __float_as_uint(f);
  u += 0x7fffu + ((u >> 16) & 1u);
  return (unsigned short)(u >> 16);
}

__device__ __forceinline__ unsigned int pack_bf16x2(float a, float b) {
  unsigned int ua = __float_as_uint(a) + 0x8000u;
  unsigned int ub = __float_as_uint(b) + 0x8000u;
  return __builtin_amdgcn_perm(ub, ua, 0x07060302u);
}

__device__ __forceinline__ float bf_lo(unsigned int u) { return __uint_as_float(u << 16); }
__device__ __forceinline__ float bf_hi(unsigned int u) { return __uint_as_float(u & 0xffff0000u); }

// async 16B global -> LDS (wave-uniform LDS base + lane*16)
__device__ __forceinline__ void glds16(const void* g, void* l) {
  __builtin_amdgcn_global_load_lds(
      (const __attribute__((address_space(1))) unsigned int*)g,
      (__attribute__((address_space(3))) unsigned int*)l, 16, 0, 0);
}

// ---------------- transpose + cast: src [K][Nn] fp32 -> dst [Nn][K] bf16 ----
// blockIdx.z = batch slice (slice stride K*Nn both sides)
__global__ __launch_bounds__(256) void transpose_cast_k(
    const float* __restrict__ src0, unsigned short* __restrict__ dst0,
    int K, int Nn)
{
  __shared__ unsigned short t[64][65];
  const size_t soff = (size_t)blockIdx.z * K * Nn;
  const float* src = src0 + soff;
  unsigned short* dst = dst0 + soff;
  const int bk = blockIdx.x * 64;
  const int bn = blockIdx.y * 64;
  const int tid = threadIdx.x;
  #pragma unroll
  for (int j = 0; j < 16; ++j) {
    int i = tid + 256 * j;
    int r = i >> 6, c = i & 63;
    t[r][c] = f32_to_bf16(src[(size_t)(bk + r) * Nn + bn + c]);
  }
  __syncthreads();
  #pragma unroll
  for (int j = 0; j < 16; ++j) {
    int i = tid + 256 * j;
    int r = i >> 6, c = i & 63;
    dst[(size_t)(bn + r) * K + bk + c] = t[c][r];
  }
}

// ---------------- graph preprocessing ----------------
__global__ __launch_bounds__(256) void deg_count_k(const int* __restrict__ dst,
                                                   int* __restrict__ deg)
{
  int e = blockIdx.x * 256 + threadIdx.x;
  atomicAdd(&deg[dst[e]], 1);
}

__global__ __launch_bounds__(256) void norm_k(const int* __restrict__ deg,
                                              float* __restrict__ nrm)
{
  int n = blockIdx.x * 256 + threadIdx.x;
  int d = deg[n];
  nrm[n] = 1.0f / sqrtf((float)(d < 1 ? 1 : d));
}

__global__ __launch_bounds__(1024) void scan_k(const int* __restrict__ deg,
                                               int* __restrict__ rp)
{
  __shared__ int sums[1024];
  const int t = threadIdx.x;
  int local[12];
  int s = 0;
  #pragma unroll
  for (int i = 0; i < 12; ++i) { local[i] = deg[t * 12 + i]; s += local[i]; }
  sums[t] = s;
  __syncthreads();
  for (int off = 1; off < 1024; off <<= 1) {
    int v = (t >= off) ? sums[t - off] : 0;
    __syncthreads();
    sums[t] += v;
    __syncthreads();
  }
  int run = (t == 0) ? 0 : sums[t - 1];
  #pragma unroll
  for (int i = 0; i < 12; ++i) { rp[t * 12 + i] = run; run += local[i]; }
  if (t == 1023) rp[12288] = run;
}

__global__ __launch_bounds__(256) void csr_fill_k(
    const int* __restrict__ src, const int* __restrict__ dst,
    const float* __restrict__ nrm, const int* __restrict__ rp,
    int* __restrict__ cur, int* __restrict__ col, float* __restrict__ wgt)
{
  int e = blockIdx.x * 256 + threadIdx.x;
  int d = dst[e];
  int p = rp[d] + atomicAdd(&cur[d], 1);
  int s = src[e];
  col[p] = s;
  wgt[p] = nrm[s] * nrm[d];
}

// ---------------- big-tile MFMA GEMM ----------------
// C[M, >=512] = A[M,K] * Bt[512-slice, K]^T.  Block: BM=128 x BN=512, 512 thr.
// B: global_load_lds (async, 16B) -> double-buffered swizzled LDS.
// A: VGPR prefetch (+ fp32->bf16 convert when AF32) -> single swizzled LDS buf.
// OUT16: epilogue packs C to bf16 (L2 merges the 32B-chunk stores).
template<bool AF32, bool OUT16>
__global__ __launch_bounds__(512, 2) void gemm_big(
    const void* __restrict__ Av, const unsigned short* __restrict__ Bt,
    void* __restrict__ Cv, int M, int Ktot, int kchunk, int ldc)
{
  __shared__ unsigned short lA[128 * 64];        // 16 KB
  __shared__ unsigned short lB[2][512 * 64];     // 2 x 64 KB  (total 144 KB)
  const int t = threadIdx.x;
  const int w = t >> 6;
  const int l = t & 63;
  const int wm = (w >> 2) * 64;
  const int wn = (w & 3) * 128;
  const int m0 = blockIdx.y * 128;
  const int n0 = blockIdx.x * 512;
  const int kbeg = blockIdx.z * kchunk;

  f32x4 acc[4][8];
  const f32x4 zero = {0.f, 0.f, 0.f, 0.f};
  #pragma unroll
  for (int i = 0; i < 4; ++i)
    #pragma unroll
    for (int j = 0; j < 8; ++j) acc[i][j] = zero;

  float4 aP32[4];
  int4   aP16[2];
  const int iters = kchunk / 64;

  // prologue: stage B(0) async, load A(0) regs
  #pragma unroll
  for (int j = 0; j < 8; ++j) {
    int i = t + 512 * j;
    int row = i >> 3;
    int gcol = ((i & 7) ^ (row & 7)) << 3;
    glds16(Bt + (size_t)(n0 + row) * Ktot + kbeg + gcol,
           &lB[0][(size_t)(j * 512 + w * 64) * 8]);
  }
  if (AF32) {
    const float* A = (const float*)Av;
    #pragma unroll
    for (int j = 0; j < 4; ++j) {
      int i = t + 512 * j;
      int row = i >> 4, c4s = i & 15;
      int gcol = ((((c4s >> 1) ^ (row & 7)) << 3)) + ((c4s & 1) << 2);
      aP32[j] = *reinterpret_cast<const float4*>(&((const float*)Av)[(size_t)(m0 + row) * Ktot + kbeg + gcol]);
      (void)A;
    }
  } else {
    #pragma unroll
    for (int j = 0; j < 2; ++j) {
      int i = t + 512 * j;
      int row = i >> 3;
      int gcol = ((i & 7) ^ (row & 7)) << 3;
      aP16[j] = *reinterpret_cast<const int4*>(&((const unsigned short*)Av)[(size_t)(m0 + row) * Ktot + kbeg + gcol]);
    }
  }
  if (AF32) {
    #pragma unroll
    for (int j = 0; j < 4; ++j) {
      int i = t + 512 * j;
      int row = i >> 4, c4s = i & 15;
      uint2 p;
      p.x = pack_bf16x2(aP32[j].x, aP32[j].y);
      p.y = pack_bf16x2(aP32[j].z, aP32[j].w);
      *reinterpret_cast<uint2*>(&lA[row * 64 + c4s * 4]) = p;
    }
  } else {
    #pragma unroll
    for (int j = 0; j < 2; ++j) {
      int i = t + 512 * j;
      int row = i >> 3;
      *reinterpret_cast<int4*>(&lA[row * 64 + (i & 7) * 8]) = aP16[j];
    }
  }
  __syncthreads();

  int bi = 0;
  for (int kt = 0; kt < iters; ++kt) {
    const int kn = kbeg + (kt + 1) * 64;
    if (kt + 1 < iters) {
      #pragma unroll
      for (int j = 0; j < 8; ++j) {
        int i = t + 512 * j;
        int row = i >> 3;
        int gcol = ((i & 7) ^ (row & 7)) << 3;
        glds16(Bt + (size_t)(n0 + row) * Ktot + kn + gcol,
               &lB[bi ^ 1][(size_t)(j * 512 + w * 64) * 8]);
      }
      if (AF32) {
        #pragma unroll
        for (int j = 0; j < 4; ++j) {
          int i = t + 512 * j;
          int row = i >> 4, c4s = i & 15;
          int gcol = ((((c4s >> 1) ^ (row & 7)) << 3)) + ((c4s & 1) << 2);
          aP32[j] = *reinterpret_cast<const float4*>(&((const float*)Av)[(size_t)(m0 + row) * Ktot + kn + gcol]);
        }
      } else {
        #pragma unroll
        for (int j = 0; j < 2; ++j) {
          int i = t + 512 * j;
          int row = i >> 3;
          int gcol = ((i & 7) ^ (row & 7)) << 3;
          aP16[j] = *reinterpret_cast<const int4*>(&((const unsigned short*)Av)[(size_t)(m0 + row) * Ktot + kn + gcol]);
        }
      }
    }
    const unsigned short* lBc = &lB[bi][0];
    #pragma unroll
    for (int ks = 0; ks < 2; ++ks) {
      const int kc = ks * 4 + (l >> 4);
      const int co = ((kc ^ (l & 7)) << 3);
      short8 af[4];
      #pragma unroll
      for (int mi = 0; mi < 4; ++mi) {
        int row = wm + mi * 16 + (l & 15);
        af[mi] = *reinterpret_cast<const short8*>(&lA[row * 64 + co]);
      }
      #pragma unroll
      for (int ni = 0; ni < 8; ++ni) {
        int brow = wn + ni * 16 + (l & 15);
        short8 bfr = *reinterpret_cast<const short8*>(&lBc[brow * 64 + co]);
        #pragma unroll
        for (int mi = 0; mi < 4; ++mi)
          acc[mi][ni] = __builtin_amdgcn_mfma_f32_16x16x32_bf16(af[mi], bfr, acc[mi][ni], 0, 0, 0);
      }
    }
    __syncthreads();
    if (kt + 1 < iters) {
      if (AF32) {
        #pragma unroll
        for (int j = 0; j < 4; ++j) {
          int i = t + 512 * j;
          int row = i >> 4, c4s = i & 15;
          uint2 p;
          p.x = pack_bf16x2(aP32[j].x, aP32[j].y);
          p.y = pack_bf16x2(aP32[j].z, aP32[j].w);
          *reinterpret_cast<uint2*>(&lA[row * 64 + c4s * 4]) = p;
        }
      } else {
        #pragma unroll
        for (int j = 0; j < 2; ++j) {
          int i = t + 512 * j;
          int row = i >> 3;
          *reinterpret_cast<int4*>(&lA[row * 64 + (i & 7) * 8]) = aP16[j];
        }
      }
    }
    __syncthreads();
    bi ^= 1;
  }
  // epilogue: C/D layout col=lane&15, row=(lane>>4)*4+reg (m89-verified)
  #pragma unroll
  for (int mi = 0; mi < 4; ++mi) {
    #pragma unroll
    for (int ni = 0; ni < 8; ++ni) {
      const int colI = n0 + wn + ni * 16 + (l & 15);
      const int rbase = m0 + wm + mi * 16 + (l >> 4) * 4;
      if (OUT16) {
        unsigned short* C16 = (unsigned short*)Cv + (size_t)blockIdx.z * M * ldc;
        #pragma unroll
        for (int r = 0; r < 4; ++r)
          C16[(size_t)(rbase + r) * ldc + colI] = f32_to_bf16(acc[mi][ni][r]);
      } else {
        float* C32 = (float*)Cv + (size_t)blockIdx.z * M * ldc;
        #pragma unroll
        for (int r = 0; r < 4; ++r)
          C32[(size_t)(rbase + r) * ldc + colI] = acc[mi][ni][r];
      }
    }
  }
}

// ---------------- reduce SPLITK partials + cast to bf16 ----------------
template<int SPLITK>
__global__ __launch_bounds__(256) void reduce_cast_k(
    const float* __restrict__ P, unsigned short* __restrict__ out, int total)
{
  int i4 = (blockIdx.x * 256 + threadIdx.x) * 4;
  float4 s = *reinterpret_cast<const float4*>(&P[i4]);
  #pragma unroll
  for (int z = 1; z < SPLITK; ++z) {
    float4 v = *reinterpret_cast<const float4*>(&P[(size_t)z * total + i4]);
    s.x += v.x; s.y += v.y; s.z += v.z; s.w += v.w;
  }
  uint2 o2;
  o2.x = pack_bf16x2(s.x, s.y);
  o2.y = pack_bf16x2(s.z, s.w);
  *reinterpret_cast<uint2*>(&out[i4]) = o2;
}

// ---------------- SpMM (bf16): Tout[n,:] = Yk[n,:] + sum_e w_e * Tin[col_e,:]
// wave per node; lane covers 8 bf16 (16B). fp32 accumulation.
__global__ __launch_bounds__(256) void spmm_bk(
    const int* __restrict__ rp, const int* __restrict__ col,
    const float* __restrict__ wgt,
    const unsigned short* __restrict__ Tin, int ldin,
    const unsigned short* __restrict__ Yk, int ldy,
    const float* __restrict__ bias,
    unsigned short* __restrict__ Tout, int addBias)
{
  const int wave = threadIdx.x >> 6;
  const int lane = threadIdx.x & 63;
  const int n = blockIdx.x * 4 + wave;
  const int c0 = lane * 8;

  uint4 y = *reinterpret_cast<const uint4*>(&Yk[(size_t)n * ldy + c0]);
  float a0 = bf_lo(y.x), a1 = bf_hi(y.x), a2 = bf_lo(y.y), a3 = bf_hi(y.y);
  float a4 = bf_lo(y.z), a5 = bf_hi(y.z), a6 = bf_lo(y.w), a7 = bf_hi(y.w);
  if (addBias) {
    float4 b0 = *reinterpret_cast<const float4*>(&bias[c0]);
    float4 b1 = *reinterpret_cast<const float4*>(&bias[c0 + 4]);
    a0 += b0.x; a1 += b0.y; a2 += b0.z; a3 += b0.w;
    a4 += b1.x; a5 += b1.y; a6 += b1.z; a7 += b1.w;
  }
  const int e1 = rp[n + 1];
  int e = rp[n];
  for (; e + 1 < e1; e += 2) {
    int s0 = col[e], s1 = col[e + 1];
    float w0 = wgt[e], w1 = wgt[e + 1];
    uint4 v0 = *reinterpret_cast<const uint4*>(&Tin[(size_t)s0 * ldin + c0]);
    uint4 v1 = *reinterpret_cast<const uint4*>(&Tin[(size_t)s1 * ldin + c0]);
    a0 += w0 * bf_lo(v0.x) + w1 * bf_lo(v1.x);
    a1 += w0 * bf_hi(v0.x) + w1 * bf_hi(v1.x);
    a2 += w0 * bf_lo(v0.y) + w1 * bf_lo(v1.y);
    a3 += w0 * bf_hi(v0.y) + w1 * bf_hi(v1.y);
    a4 += w0 * bf_lo(v0.z) + w1 * bf_lo(v1.z);
    a5 += w0 * bf_hi(v0.z) + w1 * bf_hi(v1.z);
    a6 += w0 * bf_lo(v0.w) + w1 * bf_lo(v1.w);
    a7 += w0 * bf_hi(v0.w) + w1 * bf_hi(v1.w);
  }
  if (e < e1) {
    int s0 = col[e];
    float w0 = wgt[e];
    uint4 v0 = *reinterpret_cast<const uint4*>(&Tin[(size_t)s0 * ldin + c0]);
    a0 += w0 * bf_lo(v0.x); a1 += w0 * bf_hi(v0.x);
    a2 += w0 * bf_lo(v0.y); a3 += w0 * bf_hi(v0.y);
    a4 += w0 * bf_lo(v0.z); a5 += w0 * bf_hi(v0.z);
    a6 += w0 * bf_lo(v0.w); a7 += w0 * bf_hi(v0.w);
  }
  uint4 o;
  o.x = pack_bf16x2(a0, a1);
  o.y = pack_bf16x2(a2, a3);
  o.z = pack_bf16x2(a4, a5);
  o.w = pack_bf16x2(a6, a7);
  *reinterpret_cast<uint4*>(&Tout[(size_t)n * HID + c0]) = o;
}

// ---------------- per-node predictor precompute (bf16 h) ----------------
__global__ __launch_bounds__(256) void node_ab_g_k(
    const unsigned short* __restrict__ h, const float* __restrict__ Wp,
    float* __restrict__ a, float* __restrict__ b, unsigned short* __restrict__ g)
{
  const int wave = threadIdx.x >> 6;
  const int lane = threadIdx.x & 63;
  const int n = blockIdx.x * 4 + wave;
  const int c0 = lane * 8;
  uint4 hv = *reinterpret_cast<const uint4*>(&h[(size_t)n * HID + c0]);
  float h0 = bf_lo(hv.x), h1 = bf_hi(hv.x), h2 = bf_lo(hv.y), h3 = bf_hi(hv.y);
  float h4 = bf_lo(hv.z), h5 = bf_hi(hv.z), h6 = bf_lo(hv.w), h7 = bf_hi(hv.w);
  float4 w1a = *reinterpret_cast<const float4*>(&Wp[c0]);
  float4 w1b = *reinterpret_cast<const float4*>(&Wp[c0 + 4]);
  float4 w2a = *reinterpret_cast<const float4*>(&Wp[HID + c0]);
  float4 w2b = *reinterpret_cast<const float4*>(&Wp[HID + c0 + 4]);
  float4 w3a = *reinterpret_cast<const float4*>(&Wp[2 * HID + c0]);
  float4 w3b = *reinterpret_cast<const float4*>(&Wp[2 * HID + c0 + 4]);
  float pa = h0 * w1a.x + h1 * w1a.y + h2 * w1a.z + h3 * w1a.w
           + h4 * w1b.x + h5 * w1b.y + h6 * w1b.z + h7 * w1b.w;
  float pb = h0 * w2a.x + h1 * w2a.y + h2 * w2a.z + h3 * w2a.w
           + h4 * w2b.x + h5 * w2b.y + h6 * w2b.z + h7 * w2b.w;
  if (n < N_D) {
    uint4 gv;
    gv.x = pack_bf16x2(h0 * w3a.x, h1 * w3a.y);
    gv.y = pack_bf16x2(h2 * w3a.z, h3 * w3a.w);
    gv.z = pack_bf16x2(h4 * w3b.x, h5 * w3b.y);
    gv.w = pack_bf16x2(h6 * w3b.z, h7 * w3b.w);
    *reinterpret_cast<uint4*>(&g[(size_t)n * HID + c0]) = gv;
  }
  #pragma unroll
  for (int off = 32; off > 0; off >>= 1) {
    pa += __shfl_down(pa, off);
    pb += __shfl_down(pb, off);
  }
  if (lane == 0) { a[n] = pa; b[n] = pb; }
}

// ---------------- pair scoring: wave per pair (bf16 gathers) ----------------
__global__ __launch_bounds__(256) void pairs_kernel(
    const int* __restrict__ dis, const int* __restrict__ mir,
    const unsigned short* __restrict__ h, const unsigned short* __restrict__ g,
    const float* __restrict__ a, const float* __restrict__ b,
    const float* __restrict__ bp, float* __restrict__ out)
{
  const int gw = (int)((blockIdx.x * 256 + threadIdx.x) >> 6);
  const int lane = threadIdx.x & 63;
  const int d = dis[gw];
  const int m = mir[gw];
  uint4 gv = *reinterpret_cast<const uint4*>(&g[(size_t)d * HID + lane * 8]);
  uint4 hv = *reinterpret_cast<const uint4*>(&h[(size_t)m * HID + lane * 8]);
  float s = bf_lo(gv.x) * bf_lo(hv.x) + bf_hi(gv.x) * bf_hi(hv.x)
          + bf_lo(gv.y) * bf_lo(hv.y) + bf_hi(gv.y) * bf_hi(hv.y)
          + bf_lo(gv.z) * bf_lo(hv.z) + bf_hi(gv.z) * bf_hi(hv.z)
          + bf_lo(gv.w) * bf_lo(hv.w) + bf_hi(gv.w) * bf_hi(hv.w);
  #pragma unroll
  for (int off = 32; off > 0; off >>= 1) s += __shfl_down(s, off);
  if (lane == 0) {
    float logit = s + a[d] + b[m] + bp[0];
    out[gw] = 1.0f / (1.0f + expf(-logit));
  }
}

// ---------------- launcher ----------------
extern "C" void kernel_launch(void* const* d_in, const int* in_sizes, int n_in,
                              void* d_out, int out_size, void* d_ws, size_t ws_size,
                              hipStream_t stream)
{
  const float* d_sim = (const float*)d_in[0];
  const float* m_sim = (const float*)d_in[1];
  const int*   src   = (const int*)d_in[2];
  const int*   dst   = (const int*)d_in[3];
  const int*   dis   = (const int*)d_in[4];
  const int*   mir   = (const int*)d_in[5];
  const float* Wd    = (const float*)d_in[6];
  const float* Wm    = (const float*)d_in[7];
  const float* Wf    = (const float*)d_in[8];
  const float* bf    = (const float*)d_in[9];
  const float* Wp    = (const float*)d_in[10];
  const float* bp    = (const float*)d_in[11];
  float* out = (float*)d_out;

  const size_t SZ_XB  = (size_t)NN * HID * 2;            // 12.6 MB
  const size_t SZ_TB  = (size_t)NN * HID * 2;            // 12.6 MB
  const size_t SZ_PD8 = (size_t)8 * 4096 * 512 * 4;      // 64 MB
  const size_t SZ_PM4 = (size_t)4 * 8192 * 512 * 4;      // 64 MB
  const size_t SZ_PD2 = (size_t)2 * 4096 * 512 * 4;      // 16 MB
  const size_t SZ_PM2 = (size_t)2 * 8192 * 512 * 4;      // 32 MB
  const size_t REST = SZ_XB + 2 * SZ_TB + (size_t)512*4096*2 + (size_t)512*8192*2
                    + (size_t)2560*512*2 + 49152*3 + 49664 + (size_t)EDG*8
                    + 2*49152 + (size_t)N_D*HID*2 + 65536;

  const int planA = (ws_size >= SZ_PD8 + SZ_PM4 + REST);
  const size_t R1sz = planA ? (SZ_PD8 + SZ_PM4) : (SZ_PD2 + SZ_PM2);

  char* p = (char*)d_ws;
  char* R1 = p;                 p += R1sz;
  unsigned short* Xb  = (unsigned short*)p;  p += SZ_XB;
  unsigned short* T0b = (unsigned short*)p;  p += SZ_TB;
  unsigned short* T1b = (unsigned short*)p;  p += SZ_TB;
  unsigned short* WdT = (unsigned short*)p;  p += (size_t)512 * 4096 * 2;
  unsigned short* WmT = (unsigned short*)p;  p += (size_t)512 * 8192 * 2;
  unsigned short* WfT = (unsigned short*)p;  p += (size_t)2560 * 512 * 2;
  int*   deg = (int*)p;         p += 49152;
  float* nrm = (float*)p;       p += 49152;
  int*   rp  = (int*)p;         p += 49664;
  int*   cur = (int*)p;         p += 49152;
  int*   col = (int*)p;         p += (size_t)EDG * 4;
  float* wgt = (float*)p;       p += (size_t)EDG * 4;
  float* av  = (float*)p;       p += 49152;
  float* bv  = (float*)p;       p += 49152;
  unsigned short* G = (unsigned short*)p;    p += (size_t)N_D * HID * 2;

  // ---- pack weights to bf16, transposed [N][K] (Wf: 5 slices batched) ----
  transpose_cast_k<<<dim3(64, 8, 1), 256, 0, stream>>>(Wd, WdT, 4096, 512);
  transpose_cast_k<<<dim3(128, 8, 1), 256, 0, stream>>>(Wm, WmT, 8192, 512);
  transpose_cast_k<<<dim3(8, 8, 5), 256, 0, stream>>>(Wf, WfT, 512, 512);

  // ---- graph: degrees, norms, CSR by dst ----
  hipMemsetAsync(deg, 0, 49152, stream);
  hipMemsetAsync(cur, 0, 49152, stream);
  deg_count_k<<<EDG / 256, 256, 0, stream>>>(dst, deg);
  norm_k<<<NN / 256, 256, 0, stream>>>(deg, nrm);
  scan_k<<<1, 1024, 0, stream>>>(deg, rp);
  csr_fill_k<<<EDG / 256, 256, 0, stream>>>(src, dst, nrm, rp, cur, col, wgt);

  // ---- X = [d_sim@Wd ; m_sim@Wm] : A fetched once, split-K fills 256 CUs ----
  if (planA) {
    float* Pd = (float*)R1;
    float* Pm = (float*)(R1 + SZ_PD8);
    gemm_big<true, false><<<dim3(1, 32, 8), 512, 0, stream>>>(d_sim, WdT, Pd, 4096, 4096, 512, 512);
    gemm_big<true, false><<<dim3(1, 64, 4), 512, 0, stream>>>(m_sim, WmT, Pm, 8192, 8192, 2048, 512);
    reduce_cast_k<8><<<2048, 256, 0, stream>>>(Pd, Xb, 4096 * 512);
    reduce_cast_k<4><<<4096, 256, 0, stream>>>(Pm, Xb + (size_t)4096 * 512, 8192 * 512);
  } else {
    float* Pd = (float*)R1;
    float* Pm = (float*)(R1 + SZ_PD2);
    gemm_big<true, false><<<dim3(1, 32, 2), 512, 0, stream>>>(d_sim, WdT, Pd, 4096, 4096, 2048, 512);
    gemm_big<true, false><<<dim3(1, 64, 2), 512, 0, stream>>>(m_sim, WmT, Pm, 8192, 8192, 4096, 512);
    reduce_cast_k<2><<<2048, 256, 0, stream>>>(Pd, Xb, 4096 * 512);
    reduce_cast_k<2><<<4096, 256, 0, stream>>>(Pm, Xb + (size_t)4096 * 512, 8192 * 512);
  }

  // ---- Horner: h = Y0 + A(Y1 + A(Y2 + A(Y3 + A*Y4))) + bf (bf16 chain) ----
  unsigned short* h;
  if (planA) {
    unsigned short* Yall = (unsigned short*)R1;   // 12288 x 2560 bf16 (63 MB)
    gemm_big<false, true><<<dim3(5, 96, 1), 512, 0, stream>>>(Xb, WfT, Yall, NN, 512, 512, 2560);
    spmm_bk<<<NN / 4, 256, 0, stream>>>(rp, col, wgt, Yall + 4 * 512, 2560, Yall + 3 * 512, 2560, bf, T1b, 0);
    spmm_bk<<<NN / 4, 256, 0, stream>>>(rp, col, wgt, T1b, 512, Yall + 2 * 512, 2560, bf, T0b, 0);
    spmm_bk<<<NN / 4, 256, 0, stream>>>(rp, col, wgt, T0b, 512, Yall + 1 * 512, 2560, bf, T1b, 0);
    spmm_bk<<<NN / 4, 256, 0, stream>>>(rp, col, wgt, T1b, 512, Yall + 0 * 512, 2560, bf, T0b, 1);
    h = T0b;
  } else {
    unsigned short* Qb = (unsigned short*)R1;     // one bf16 Y-slice at a time
    gemm_big<false, true><<<dim3(1, 96, 1), 512, 0, stream>>>(Xb, WfT + (size_t)4 * 512 * 512, T1b, NN, 512, 512, 512);
    gemm_big<false, true><<<dim3(1, 96, 1), 512, 0, stream>>>(Xb, WfT + (size_t)3 * 512 * 512, Qb, NN, 512, 512, 512);
    spmm_bk<<<NN / 4, 256, 0, stream>>>(rp, col, wgt, T1b, 512, Qb, 512, bf, T0b, 0);
    gemm_big<false, true><<<dim3(1, 96, 1), 512, 0, stream>>>(Xb, WfT + (size_t)2 * 512 * 512, Qb, NN, 512, 512, 512);
    spmm_bk<<<NN / 4, 256, 0, stream>>>(rp, col, wgt, T0b, 512, Qb, 512, bf, T1b, 0);
    gemm_big<false, true><<<dim3(1, 96, 1), 512, 0, stream>>>(Xb, WfT + (size_t)1 * 512 * 512, Qb, NN, 512, 512, 512);
    spmm_bk<<<NN / 4, 256, 0, stream>>>(rp, col, wgt, T1b, 512, Qb, 512, bf, T0b, 0);
    gemm_big<false, true><<<dim3(1, 96, 1), 512, 0, stream>>>(Xb, WfT + (size_t)0 * 512 * 512, Qb, NN, 512, 512, 512);
    spmm_bk<<<NN / 4, 256, 0, stream>>>(rp, col, wgt, T0b, 512, Qb, 512, bf, T1b, 1);
    h = T1b;
  }

  // ---- predictor ----
  node_ab_g_k<<<NN / 4, 256, 0, stream>>>(h, Wp, av, bv, G);
  pairs_kernel<<<NPAIR / 4, 256, 0, stream>>>(dis, mir, h, G, av, bv, bp, out);
}